// Round 7
// baseline (911.491 us; speedup 1.0000x reference)
//
#include <hip/hip_runtime.h>

#define IN_DIM  512
#define HID_DIM 256
#define OUT_DIM 64
#define KPROP   5
#define ALPHA   0.1f

typedef short short8v __attribute__((ext_vector_type(8)));
typedef float f32x4   __attribute__((ext_vector_type(4)));

__device__ __forceinline__ unsigned short f2bf(float f) {
    unsigned u = __builtin_bit_cast(unsigned, f);
    unsigned r = (u + 0x7FFFu + ((u >> 16) & 1u)) >> 16;
    return (unsigned short)r;
}
__device__ __forceinline__ float bflo(unsigned v) { return __builtin_bit_cast(float, v << 16); }
__device__ __forceinline__ float bfhi(unsigned v) { return __builtin_bit_cast(float, v & 0xffff0000u); }

// ---------------- degree histogram over dst (col) ----------------
__global__ __launch_bounds__(256) void hist_kernel(const int* __restrict__ ei, int E,
                                                   int* __restrict__ counts) {
    int e = blockIdx.x * 256 + threadIdx.x;
    if (e < E) atomicAdd(&counts[ei[E + e]], 1);
}

__global__ __launch_bounds__(256) void dinv_kernel(const int* __restrict__ counts,
                                                   float* __restrict__ dinv, int N) {
    int i = blockIdx.x * 256 + threadIdx.x;
    if (i < N) dinv[i] = rsqrtf((float)(counts[i] + 1));
}

// ---------------- exclusive scan (3 kernels) ----------------
__global__ __launch_bounds__(256) void scan1_kernel(const int* __restrict__ counts,
                                                    int* __restrict__ indptr,
                                                    int* __restrict__ bsum, int N) {
    __shared__ int sm[256];
    int t = threadIdx.x;
    int base = blockIdx.x * 1024 + t * 4;
    int v0 = 0, v1 = 0, v2 = 0, v3 = 0;
    if (base + 0 < N) v0 = counts[base + 0];
    if (base + 1 < N) v1 = counts[base + 1];
    if (base + 2 < N) v2 = counts[base + 2];
    if (base + 3 < N) v3 = counts[base + 3];
    int s = v0 + v1 + v2 + v3;
    sm[t] = s;
    __syncthreads();
    for (int off = 1; off < 256; off <<= 1) {
        int add = 0;
        if (t >= off) add = sm[t - off];
        __syncthreads();
        if (t >= off) sm[t] += add;
        __syncthreads();
    }
    int run = sm[t] - s;
    if (base + 0 < N) indptr[base + 0] = run; run += v0;
    if (base + 1 < N) indptr[base + 1] = run; run += v1;
    if (base + 2 < N) indptr[base + 2] = run; run += v2;
    if (base + 3 < N) indptr[base + 3] = run;
    if (t == 255) bsum[blockIdx.x] = sm[255];
}

__global__ __launch_bounds__(256) void scan2_kernel(const int* __restrict__ bsum,
                                                    int* __restrict__ boff, int nb,
                                                    int* __restrict__ indptr, int N) {
    __shared__ int sm[256];
    int t = threadIdx.x;
    int v = (t < nb) ? bsum[t] : 0;
    sm[t] = v;
    __syncthreads();
    for (int off = 1; off < 256; off <<= 1) {
        int add = 0;
        if (t >= off) add = sm[t - off];
        __syncthreads();
        if (t >= off) sm[t] += add;
        __syncthreads();
    }
    boff[t] = sm[t] - v;
    if (t == 255) indptr[N] = sm[255];
}

__global__ __launch_bounds__(256) void scan3_kernel(int* __restrict__ indptr,
                                                    const int* __restrict__ boff, int N) {
    int i = blockIdx.x * 256 + threadIdx.x;
    if (i < N) indptr[i] += boff[i >> 10];
}

// ---------------- CSR scatter ----------------
__global__ __launch_bounds__(256) void scatter_kernel(const int* __restrict__ ei, int E,
                                                      const int* __restrict__ indptr,
                                                      int* __restrict__ fill,
                                                      int* __restrict__ csr_row) {
    int e = blockIdx.x * 256 + threadIdx.x;
    if (e < E) {
        int c = ei[E + e];
        int pos = indptr[c] + atomicAdd(&fill[c], 1);
        csr_row[pos] = ei[e];
    }
}

// ---------------- weight prep ----------------
__global__ __launch_bounds__(256) void prep_w1_kernel(const float* __restrict__ W1,
                                                      unsigned short* __restrict__ w1p) {
    int idx = blockIdx.x * 256 + threadIdx.x;
    int q = idx >> 14;
    int rem = idx & 16383;
    int c = rem >> 6, j = rem & 63;
    w1p[idx] = f2bf(W1[(size_t)(q * 64 + j) * HID_DIM + c]);
}

__global__ __launch_bounds__(256) void prep_w2_kernel(const float* __restrict__ W2,
                                                      unsigned short* __restrict__ w2p) {
    int idx = blockIdx.x * 256 + threadIdx.x;
    int c = idx >> 8, k = idx & 255;
    w2p[idx] = f2bf(W2[(size_t)k * OUT_DIM + c]);
}

// ---------------- MFMA MLP with T14 async-STAGE pipeline ----------------
// 64 rows/block, 4 waves. Chunk q+1's global loads issue into registers right
// after the barrier that opens chunk q's compute; regs->LDS at next iter top.
struct __align__(16) MlpSmem {
    union {
        struct {
            unsigned short xs[64][72];
            unsigned short ws[256][72];
        };
        unsigned short w2s[64][264];
    };
    unsigned short hid[64][264];
};

__global__ __launch_bounds__(256) void mlp_mfma_kernel(const float* __restrict__ x,
                                                       const unsigned short* __restrict__ w1p,
                                                       const float* __restrict__ b1,
                                                       const unsigned short* __restrict__ w2p,
                                                       const float* __restrict__ b2,
                                                       float* __restrict__ h0, int N) {
    __shared__ MlpSmem sm;
    int t = threadIdx.x;
    int w = t >> 6, l = t & 63;
    int l15 = l & 15, l4 = l >> 4;
    int wr0 = w * 16;
    int row0 = blockIdx.x * 64;

    f32x4 acc[16];
#pragma unroll
    for (int i = 0; i < 16; ++i) acc[i] = (f32x4){0.f, 0.f, 0.f, 0.f};

    float4 xr[4];   // register prefetch: x chunk
    uint4  wv[8];   // register prefetch: W1 chunk

    auto LOADX = [&](int q) {
#pragma unroll
        for (int i = 0; i < 4; ++i) {
            int e = t * 4 + i * 1024;
            int r = e >> 6, j = e & 63;
            xr[i] = make_float4(0.f, 0.f, 0.f, 0.f);
            if (row0 + r < N)
                xr[i] = *(const float4*)&x[(size_t)(row0 + r) * IN_DIM + q * 64 + j];
        }
    };
    auto LOADW = [&](int q) {
        const unsigned short* src = w1p + q * 16384;
#pragma unroll
        for (int i = 0; i < 8; ++i) wv[i] = *(const uint4*)&src[t * 8 + i * 2048];
    };

    LOADX(0);
    LOADW(0);

    for (int q = 0; q < 8; ++q) {
        __syncthreads();  // all waves done reading previous chunk (no-op at q=0)
        // regs -> LDS (bf16 convert x here)
#pragma unroll
        for (int i = 0; i < 4; ++i) {
            int e = t * 4 + i * 1024;
            int r = e >> 6, j = e & 63;
            unsigned u0 = (unsigned)f2bf(xr[i].x) | ((unsigned)f2bf(xr[i].y) << 16);
            unsigned u1 = (unsigned)f2bf(xr[i].z) | ((unsigned)f2bf(xr[i].w) << 16);
            *(uint2*)&sm.xs[r][j] = make_uint2(u0, u1);
        }
#pragma unroll
        for (int i = 0; i < 8; ++i) {
            int e = t * 8 + i * 2048;
            int c = e >> 6, j = e & 63;
            *(uint4*)&sm.ws[c][j] = wv[i];
        }
        __syncthreads();
        if (q < 7) {  // issue next chunk's loads; in flight during MFMA below
            LOADX(q + 1);
            LOADW(q + 1);
        }
#pragma unroll
        for (int s = 0; s < 2; ++s) {
            short8v a = *(const short8v*)&sm.xs[wr0 + l15][s * 32 + l4 * 8];
#pragma unroll
            for (int tc = 0; tc < 16; ++tc) {
                short8v b = *(const short8v*)&sm.ws[tc * 16 + l15][s * 32 + l4 * 8];
                acc[tc] = __builtin_amdgcn_mfma_f32_16x16x32_bf16(a, b, acc[tc], 0, 0, 0);
            }
        }
    }
    __syncthreads();  // done reading last chunk before hid/w2s overwrite

#pragma unroll
    for (int tc = 0; tc < 16; ++tc) {
        float bv = b1[tc * 16 + l15];
#pragma unroll
        for (int i = 0; i < 4; ++i) {
            float v = fmaxf(acc[tc][i] + bv, 0.f);
            sm.hid[wr0 + l4 * 4 + i][tc * 16 + l15] = f2bf(v);
        }
    }
#pragma unroll
    for (int i = 0; i < 8; ++i) {
        int e = t * 8 + i * 2048;
        int c = e >> 8, k = e & 255;
        *(uint4*)&sm.w2s[c][k] = *(const uint4*)&w2p[e];
    }
    __syncthreads();

    f32x4 acc2[4];
#pragma unroll
    for (int i = 0; i < 4; ++i) acc2[i] = (f32x4){0.f, 0.f, 0.f, 0.f};
#pragma unroll
    for (int s = 0; s < 8; ++s) {
        short8v a = *(const short8v*)&sm.hid[wr0 + l15][s * 32 + l4 * 8];
#pragma unroll
        for (int tc = 0; tc < 4; ++tc) {
            short8v b = *(const short8v*)&sm.w2s[tc * 16 + l15][s * 32 + l4 * 8];
            acc2[tc] = __builtin_amdgcn_mfma_f32_16x16x32_bf16(a, b, acc2[tc], 0, 0, 0);
        }
    }
#pragma unroll
    for (int tc = 0; tc < 4; ++tc) {
        float bv = b2[tc * 16 + l15];
#pragma unroll
        for (int i = 0; i < 4; ++i) {
            int row = row0 + wr0 + l4 * 4 + i;
            if (row < N) h0[(size_t)row * OUT_DIM + tc * 16 + l15] = acc2[tc][i] + bv;
        }
    }
}

// ---------------- hs init: hs[i] = bf16(dinv[i] * h0[i]) ----------------
__global__ __launch_bounds__(256) void hs_init_kernel(const float* __restrict__ h0,
                                                      const float* __restrict__ dinv,
                                                      unsigned short* __restrict__ hs, int N) {
    int idx = blockIdx.x * 256 + threadIdx.x;
    if (idx >= N * 16) return;
    int node = idx >> 4;
    int j = (idx & 15) * 4;
    float d = dinv[node];
    float4 v = *(const float4*)&h0[(size_t)node * 64 + j];
    ushort4 o;
    o.x = f2bf(d * v.x);
    o.y = f2bf(d * v.y);
    o.z = f2bf(d * v.z);
    o.w = f2bf(d * v.w);
    *(ushort4*)&hs[(size_t)node * 64 + j] = o;
}

// ---------------- propagation, bf16 prescaled + idx software pipeline ----------------
__global__ __launch_bounds__(256) void prop_bf16_kernel(const unsigned short* __restrict__ hs,
                                                        const float* __restrict__ h0,
                                                        const float* __restrict__ dinv,
                                                        const int* __restrict__ csr_row,
                                                        const int* __restrict__ indptr,
                                                        unsigned short* __restrict__ hs_out,
                                                        float* __restrict__ hfin,
                                                        int last, int N) {
    int node = blockIdx.x * 4 + (threadIdx.x >> 6);
    if (node >= N) return;
    int l = threadIdx.x & 63;
    int half = l >> 5, li = l & 31;
    const unsigned* hs32 = (const unsigned*)hs;
    int beg = indptr[node], end = indptr[node + 1];
    float a0 = 0.f, a1 = 0.f;
    int e = beg;
    if (e + 8 <= end) {
        // preload first trip's indices
        int r0 = csr_row[e + 0 + half];
        int r1 = csr_row[e + 2 + half];
        int r2 = csr_row[e + 4 + half];
        int r3 = csr_row[e + 6 + half];
        while (true) {
            // prefetch next trip's indices during this trip's gathers
            // (clamped source: harmless reload of beg when no next trip)
            int eb = (e + 16 <= end) ? (e + 8) : beg;
            int n0 = csr_row[eb + 0 + half];
            int n1 = csr_row[eb + 2 + half];
            int n2 = csr_row[eb + 4 + half];
            int n3 = csr_row[eb + 6 + half];
            unsigned v0 = hs32[(size_t)r0 * 32 + li];
            unsigned v1 = hs32[(size_t)r1 * 32 + li];
            unsigned v2 = hs32[(size_t)r2 * 32 + li];
            unsigned v3 = hs32[(size_t)r3 * 32 + li];
            a0 += bflo(v0); a1 += bfhi(v0);
            a0 += bflo(v1); a1 += bfhi(v1);
            a0 += bflo(v2); a1 += bfhi(v2);
            a0 += bflo(v3); a1 += bfhi(v3);
            e += 8;
            if (e + 8 > end) break;
            r0 = n0; r1 = n1; r2 = n2; r3 = n3;
        }
    }
    for (; e + 2 <= end; e += 2) {
        int r = csr_row[e + half];
        unsigned v = hs32[(size_t)r * 32 + li];
        a0 += bflo(v); a1 += bfhi(v);
    }
    if (e < end && half == 0) {
        int r = csr_row[e];
        unsigned v = hs32[(size_t)r * 32 + li];
        a0 += bflo(v); a1 += bfhi(v);
    }
    a0 += __shfl_xor(a0, 32);
    a1 += __shfl_xor(a1, 32);
    unsigned vs = hs32[(size_t)node * 32 + li];  // self loop
    a0 += bflo(vs);
    a1 += bfhi(vs);
    float dcn = dinv[node];
    float2 z = *(const float2*)&h0[(size_t)node * 64 + li * 2];
    float o0 = (1.0f - ALPHA) * (dcn * a0) + ALPHA * z.x;
    float o1 = (1.0f - ALPHA) * (dcn * a1) + ALPHA * z.y;
    if (half == 0) {
        if (last) {
            *(float2*)&hfin[(size_t)node * 64 + li * 2] = make_float2(o0, o1);
        } else {
            unsigned p = (unsigned)f2bf(dcn * o0) | ((unsigned)f2bf(dcn * o1) << 16);
            ((unsigned*)hs_out)[(size_t)node * 32 + li] = p;
        }
    }
}

// ---------------- log_softmax (in-place safe) ----------------
__global__ __launch_bounds__(256) void lsm_kernel(const float* __restrict__ h,
                                                  float* __restrict__ out, int N) {
    int node = blockIdx.x * 4 + (threadIdx.x >> 6);
    if (node >= N) return;
    int lane = threadIdx.x & 63;
    float v = h[(size_t)node * 64 + lane];
    float m = v;
    for (int off = 32; off > 0; off >>= 1) m = fmaxf(m, __shfl_xor(m, off));
    float ex = expf(v - m);
    float s = ex;
    for (int off = 32; off > 0; off >>= 1) s += __shfl_xor(s, off);
    out[(size_t)node * 64 + lane] = (v - m) - logf(s);
}

extern "C" void kernel_launch(void* const* d_in, const int* in_sizes, int n_in,
                              void* d_out, int out_size, void* d_ws, size_t ws_size,
                              hipStream_t stream) {
    const float* x  = (const float*)d_in[0];
    const int*   ei = (const int*)d_in[1];
    const float* W1 = (const float*)d_in[2];
    const float* b1 = (const float*)d_in[3];
    const float* W2 = (const float*)d_in[4];
    const float* b2 = (const float*)d_in[5];
    float* out = (float*)d_out;
    int N = in_sizes[0] / IN_DIM;
    int E = in_sizes[1] / 2;

    char* ws = (char*)d_ws;
    size_t off = 0;
    auto alloc = [&](size_t bytes) -> void* {
        void* p = ws + off;
        off += (bytes + 255) & ~(size_t)255;
        return p;
    };
    float* h0     = (float*)alloc((size_t)N * OUT_DIM * 4);
    float* dinv   = (float*)alloc((size_t)N * 4);
    int*   counts = (int*)alloc((size_t)N * 4);
    int*   fill   = (int*)alloc((size_t)N * 4);
    int*   indptr = (int*)alloc((size_t)(N + 1) * 4);
    int*   bsum   = (int*)alloc(256 * 4);
    int*   boff   = (int*)alloc(256 * 4);
    int*   csr_row= (int*)alloc((size_t)E * 4);
    unsigned short* w1p = (unsigned short*)alloc((size_t)IN_DIM * HID_DIM * 2);
    unsigned short* w2p = (unsigned short*)alloc((size_t)HID_DIM * OUT_DIM * 2);
    unsigned short* hsA = (unsigned short*)alloc((size_t)N * OUT_DIM * 2);
    unsigned short* hsB = (unsigned short*)alloc((size_t)N * OUT_DIM * 2);
    (void)ws_size; (void)n_in; (void)out_size;

    hipMemsetAsync(counts, 0, (size_t)N * 4, stream);
    hipMemsetAsync(fill, 0, (size_t)N * 4, stream);

    prep_w1_kernel<<<(IN_DIM * HID_DIM) / 256, 256, 0, stream>>>(W1, w1p);
    prep_w2_kernel<<<(HID_DIM * OUT_DIM) / 256, 256, 0, stream>>>(W2, w2p);

    hist_kernel<<<(E + 255) / 256, 256, 0, stream>>>(ei, E, counts);
    dinv_kernel<<<(N + 255) / 256, 256, 0, stream>>>(counts, dinv, N);

    int nb = (N + 1023) / 1024;
    scan1_kernel<<<nb, 256, 0, stream>>>(counts, indptr, bsum, N);
    scan2_kernel<<<1, 256, 0, stream>>>(bsum, boff, nb, indptr, N);
    scan3_kernel<<<(N + 255) / 256, 256, 0, stream>>>(indptr, boff, N);
    scatter_kernel<<<(E + 255) / 256, 256, 0, stream>>>(ei, E, indptr, fill, csr_row);

    mlp_mfma_kernel<<<(N + 63) / 64, 256, 0, stream>>>(x, w1p, b1, w2p, b2, h0, N);

    hs_init_kernel<<<(N * 16 + 255) / 256, 256, 0, stream>>>(h0, dinv, hsA, N);

    int pb = (N + 3) / 4;
    for (int it = 0; it < KPROP; ++it) {
        const unsigned short* hin = (it % 2 == 0) ? hsA : hsB;
        unsigned short* hout = (it % 2 == 0) ? hsB : hsA;
        int last = (it == KPROP - 1) ? 1 : 0;
        prop_bf16_kernel<<<pb, 256, 0, stream>>>(hin, h0, dinv, csr_row, indptr,
                                                 hout, out, last, N);
    }
    lsm_kernel<<<pb, 256, 0, stream>>>(out, out, N);
}

// Round 8
// 786.875 us; speedup vs baseline: 1.1584x; 1.1584x over previous
//
#include <hip/hip_runtime.h>

#define IN_DIM  512
#define HID_DIM 256
#define OUT_DIM 64
#define KPROP   5
#define ALPHA   0.1f

typedef short short8v __attribute__((ext_vector_type(8)));
typedef float f32x4   __attribute__((ext_vector_type(4)));

__device__ __forceinline__ unsigned short f2bf(float f) {
    unsigned u = __builtin_bit_cast(unsigned, f);
    unsigned r = (u + 0x7FFFu + ((u >> 16) & 1u)) >> 16;
    return (unsigned short)r;
}
__device__ __forceinline__ float bflo(unsigned v) { return __builtin_bit_cast(float, v << 16); }
__device__ __forceinline__ float bfhi(unsigned v) { return __builtin_bit_cast(float, v & 0xffff0000u); }

// ---------------- degree histogram over dst (col) ----------------
__global__ __launch_bounds__(256) void hist_kernel(const int* __restrict__ ei, int E,
                                                   int* __restrict__ counts) {
    int e = blockIdx.x * 256 + threadIdx.x;
    if (e < E) atomicAdd(&counts[ei[E + e]], 1);
}

__global__ __launch_bounds__(256) void dinv_kernel(const int* __restrict__ counts,
                                                   float* __restrict__ dinv, int N) {
    int i = blockIdx.x * 256 + threadIdx.x;
    if (i < N) dinv[i] = rsqrtf((float)(counts[i] + 1));
}

// ---------------- exclusive scan (3 kernels) ----------------
__global__ __launch_bounds__(256) void scan1_kernel(const int* __restrict__ counts,
                                                    int* __restrict__ indptr,
                                                    int* __restrict__ bsum, int N) {
    __shared__ int sm[256];
    int t = threadIdx.x;
    int base = blockIdx.x * 1024 + t * 4;
    int v0 = 0, v1 = 0, v2 = 0, v3 = 0;
    if (base + 0 < N) v0 = counts[base + 0];
    if (base + 1 < N) v1 = counts[base + 1];
    if (base + 2 < N) v2 = counts[base + 2];
    if (base + 3 < N) v3 = counts[base + 3];
    int s = v0 + v1 + v2 + v3;
    sm[t] = s;
    __syncthreads();
    for (int off = 1; off < 256; off <<= 1) {
        int add = 0;
        if (t >= off) add = sm[t - off];
        __syncthreads();
        if (t >= off) sm[t] += add;
        __syncthreads();
    }
    int run = sm[t] - s;
    if (base + 0 < N) indptr[base + 0] = run; run += v0;
    if (base + 1 < N) indptr[base + 1] = run; run += v1;
    if (base + 2 < N) indptr[base + 2] = run; run += v2;
    if (base + 3 < N) indptr[base + 3] = run;
    if (t == 255) bsum[blockIdx.x] = sm[255];
}

__global__ __launch_bounds__(256) void scan2_kernel(const int* __restrict__ bsum,
                                                    int* __restrict__ boff, int nb,
                                                    int* __restrict__ indptr, int N) {
    __shared__ int sm[256];
    int t = threadIdx.x;
    int v = (t < nb) ? bsum[t] : 0;
    sm[t] = v;
    __syncthreads();
    for (int off = 1; off < 256; off <<= 1) {
        int add = 0;
        if (t >= off) add = sm[t - off];
        __syncthreads();
        if (t >= off) sm[t] += add;
        __syncthreads();
    }
    boff[t] = sm[t] - v;
    if (t == 255) indptr[N] = sm[255];
}

__global__ __launch_bounds__(256) void scan3_kernel(int* __restrict__ indptr,
                                                    const int* __restrict__ boff, int N) {
    int i = blockIdx.x * 256 + threadIdx.x;
    if (i < N) indptr[i] += boff[i >> 10];
}

// ---------------- CSR scatter ----------------
__global__ __launch_bounds__(256) void scatter_kernel(const int* __restrict__ ei, int E,
                                                      const int* __restrict__ indptr,
                                                      int* __restrict__ fill,
                                                      int* __restrict__ csr_row) {
    int e = blockIdx.x * 256 + threadIdx.x;
    if (e < E) {
        int c = ei[E + e];
        int pos = indptr[c] + atomicAdd(&fill[c], 1);
        csr_row[pos] = ei[e];
    }
}

// ---------------- weight prep ----------------
__global__ __launch_bounds__(256) void prep_w1_kernel(const float* __restrict__ W1,
                                                      unsigned short* __restrict__ w1p) {
    int idx = blockIdx.x * 256 + threadIdx.x;
    int q = idx >> 14;
    int rem = idx & 16383;
    int c = rem >> 6, j = rem & 63;
    w1p[idx] = f2bf(W1[(size_t)(q * 64 + j) * HID_DIM + c]);
}

__global__ __launch_bounds__(256) void prep_w2_kernel(const float* __restrict__ W2,
                                                      unsigned short* __restrict__ w2p) {
    int idx = blockIdx.x * 256 + threadIdx.x;
    int c = idx >> 8, k = idx & 255;
    w2p[idx] = f2bf(W2[(size_t)k * OUT_DIM + c]);
}

// ---------------- MFMA MLP, T14 async-STAGE, spill-proofed ----------------
// 64 rows/block, 4 waves. Named prefetch registers (no arrays, no lambdas);
// __launch_bounds__(256,2): LDS already caps us at 2 blocks/CU = 2 waves/SIMD,
// so a 256-VGPR budget costs nothing and prevents the r7 scratch spill.
struct __align__(16) MlpSmem {
    union {
        struct {
            unsigned short xs[64][72];
            unsigned short ws[256][72];
        };
        unsigned short w2s[64][264];
    };
    unsigned short hid[64][264];
};

__device__ __forceinline__ float4 ldx1(const float* __restrict__ x, int row0, int N,
                                       int t, int i, int q) {
    int e = t * 4 + i * 1024;
    int r = e >> 6, j = e & 63;
    if (row0 + r < N) return *(const float4*)&x[(size_t)(row0 + r) * IN_DIM + q * 64 + j];
    return make_float4(0.f, 0.f, 0.f, 0.f);
}

__global__ __launch_bounds__(256, 2) void mlp_mfma_kernel(const float* __restrict__ x,
                                                          const unsigned short* __restrict__ w1p,
                                                          const float* __restrict__ b1,
                                                          const unsigned short* __restrict__ w2p,
                                                          const float* __restrict__ b2,
                                                          float* __restrict__ h0, int N) {
    __shared__ MlpSmem sm;
    int t = threadIdx.x;
    int w = t >> 6, l = t & 63;
    int l15 = l & 15, l4 = l >> 4;
    int wr0 = w * 16;
    int row0 = blockIdx.x * 64;

    f32x4 acc[16];
#pragma unroll
    for (int i = 0; i < 16; ++i) acc[i] = (f32x4){0.f, 0.f, 0.f, 0.f};

    float4 xr0, xr1, xr2, xr3;
    uint4 wv0, wv1, wv2, wv3, wv4, wv5, wv6, wv7;

#define LOADX(q) do { \
        xr0 = ldx1(x, row0, N, t, 0, (q)); \
        xr1 = ldx1(x, row0, N, t, 1, (q)); \
        xr2 = ldx1(x, row0, N, t, 2, (q)); \
        xr3 = ldx1(x, row0, N, t, 3, (q)); \
    } while (0)
#define LOADW(q) do { \
        const unsigned short* _s = w1p + (q) * 16384; \
        wv0 = *(const uint4*)&_s[t * 8 + 0 * 2048]; \
        wv1 = *(const uint4*)&_s[t * 8 + 1 * 2048]; \
        wv2 = *(const uint4*)&_s[t * 8 + 2 * 2048]; \
        wv3 = *(const uint4*)&_s[t * 8 + 3 * 2048]; \
        wv4 = *(const uint4*)&_s[t * 8 + 4 * 2048]; \
        wv5 = *(const uint4*)&_s[t * 8 + 5 * 2048]; \
        wv6 = *(const uint4*)&_s[t * 8 + 6 * 2048]; \
        wv7 = *(const uint4*)&_s[t * 8 + 7 * 2048]; \
    } while (0)
#define STX(i, v) do { \
        int e = t * 4 + (i) * 1024; \
        int r = e >> 6, j = e & 63; \
        unsigned u0 = (unsigned)f2bf((v).x) | ((unsigned)f2bf((v).y) << 16); \
        unsigned u1 = (unsigned)f2bf((v).z) | ((unsigned)f2bf((v).w) << 16); \
        *(uint2*)&sm.xs[r][j] = make_uint2(u0, u1); \
    } while (0)
#define STW(i, v) do { \
        int e = t * 8 + (i) * 2048; \
        int c = e >> 6, j = e & 63; \
        *(uint4*)&sm.ws[c][j] = (v); \
    } while (0)

    LOADX(0);
    LOADW(0);

    for (int q = 0; q < 8; ++q) {
        __syncthreads();  // all waves done reading previous chunk (no-op at q=0)
        STX(0, xr0); STX(1, xr1); STX(2, xr2); STX(3, xr3);
        STW(0, wv0); STW(1, wv1); STW(2, wv2); STW(3, wv3);
        STW(4, wv4); STW(5, wv5); STW(6, wv6); STW(7, wv7);
        __syncthreads();
        if (q < 7) {  // issue next chunk's loads; in flight during MFMA below
            LOADX(q + 1);
            LOADW(q + 1);
        }
#pragma unroll
        for (int s = 0; s < 2; ++s) {
            short8v a = *(const short8v*)&sm.xs[wr0 + l15][s * 32 + l4 * 8];
#pragma unroll
            for (int tc = 0; tc < 16; ++tc) {
                short8v b = *(const short8v*)&sm.ws[tc * 16 + l15][s * 32 + l4 * 8];
                acc[tc] = __builtin_amdgcn_mfma_f32_16x16x32_bf16(a, b, acc[tc], 0, 0, 0);
            }
        }
    }
    __syncthreads();  // done reading last chunk before hid/w2s overwrite

#pragma unroll
    for (int tc = 0; tc < 16; ++tc) {
        float bv = b1[tc * 16 + l15];
#pragma unroll
        for (int i = 0; i < 4; ++i) {
            float v = fmaxf(acc[tc][i] + bv, 0.f);
            sm.hid[wr0 + l4 * 4 + i][tc * 16 + l15] = f2bf(v);
        }
    }
#pragma unroll
    for (int i = 0; i < 8; ++i) {
        int e = t * 8 + i * 2048;
        int c = e >> 8, k = e & 255;
        *(uint4*)&sm.w2s[c][k] = *(const uint4*)&w2p[e];
    }
    __syncthreads();

    f32x4 acc2[4];
#pragma unroll
    for (int i = 0; i < 4; ++i) acc2[i] = (f32x4){0.f, 0.f, 0.f, 0.f};
#pragma unroll
    for (int s = 0; s < 8; ++s) {
        short8v a = *(const short8v*)&sm.hid[wr0 + l15][s * 32 + l4 * 8];
#pragma unroll
        for (int tc = 0; tc < 4; ++tc) {
            short8v b = *(const short8v*)&sm.w2s[tc * 16 + l15][s * 32 + l4 * 8];
            acc2[tc] = __builtin_amdgcn_mfma_f32_16x16x32_bf16(a, b, acc2[tc], 0, 0, 0);
        }
    }
#pragma unroll
    for (int tc = 0; tc < 4; ++tc) {
        float bv = b2[tc * 16 + l15];
#pragma unroll
        for (int i = 0; i < 4; ++i) {
            int row = row0 + wr0 + l4 * 4 + i;
            if (row < N) h0[(size_t)row * OUT_DIM + tc * 16 + l15] = acc2[tc][i] + bv;
        }
    }
#undef LOADX
#undef LOADW
#undef STX
#undef STW
}

// ---------------- hs init: hs[i] = bf16(dinv[i] * h0[i]) ----------------
__global__ __launch_bounds__(256) void hs_init_kernel(const float* __restrict__ h0,
                                                      const float* __restrict__ dinv,
                                                      unsigned short* __restrict__ hs, int N) {
    int idx = blockIdx.x * 256 + threadIdx.x;
    if (idx >= N * 16) return;
    int node = idx >> 4;
    int j = (idx & 15) * 4;
    float d = dinv[node];
    float4 v = *(const float4*)&h0[(size_t)node * 64 + j];
    ushort4 o;
    o.x = f2bf(d * v.x);
    o.y = f2bf(d * v.y);
    o.z = f2bf(d * v.z);
    o.w = f2bf(d * v.w);
    *(ushort4*)&hs[(size_t)node * 64 + j] = o;
}

// ---------------- propagation, bf16 prescaled + idx software pipeline ----------------
__global__ __launch_bounds__(256) void prop_bf16_kernel(const unsigned short* __restrict__ hs,
                                                        const float* __restrict__ h0,
                                                        const float* __restrict__ dinv,
                                                        const int* __restrict__ csr_row,
                                                        const int* __restrict__ indptr,
                                                        unsigned short* __restrict__ hs_out,
                                                        float* __restrict__ hfin,
                                                        int last, int N) {
    int node = blockIdx.x * 4 + (threadIdx.x >> 6);
    if (node >= N) return;
    int l = threadIdx.x & 63;
    int half = l >> 5, li = l & 31;
    const unsigned* hs32 = (const unsigned*)hs;
    int beg = indptr[node], end = indptr[node + 1];
    float a0 = 0.f, a1 = 0.f;
    int e = beg;
    if (e + 8 <= end) {
        int r0 = csr_row[e + 0 + half];
        int r1 = csr_row[e + 2 + half];
        int r2 = csr_row[e + 4 + half];
        int r3 = csr_row[e + 6 + half];
        while (true) {
            int eb = (e + 16 <= end) ? (e + 8) : beg;
            int n0 = csr_row[eb + 0 + half];
            int n1 = csr_row[eb + 2 + half];
            int n2 = csr_row[eb + 4 + half];
            int n3 = csr_row[eb + 6 + half];
            unsigned v0 = hs32[(size_t)r0 * 32 + li];
            unsigned v1 = hs32[(size_t)r1 * 32 + li];
            unsigned v2 = hs32[(size_t)r2 * 32 + li];
            unsigned v3 = hs32[(size_t)r3 * 32 + li];
            a0 += bflo(v0); a1 += bfhi(v0);
            a0 += bflo(v1); a1 += bfhi(v1);
            a0 += bflo(v2); a1 += bfhi(v2);
            a0 += bflo(v3); a1 += bfhi(v3);
            e += 8;
            if (e + 8 > end) break;
            r0 = n0; r1 = n1; r2 = n2; r3 = n3;
        }
    }
    for (; e + 2 <= end; e += 2) {
        int r = csr_row[e + half];
        unsigned v = hs32[(size_t)r * 32 + li];
        a0 += bflo(v); a1 += bfhi(v);
    }
    if (e < end && half == 0) {
        int r = csr_row[e];
        unsigned v = hs32[(size_t)r * 32 + li];
        a0 += bflo(v); a1 += bfhi(v);
    }
    a0 += __shfl_xor(a0, 32);
    a1 += __shfl_xor(a1, 32);
    unsigned vs = hs32[(size_t)node * 32 + li];  // self loop
    a0 += bflo(vs);
    a1 += bfhi(vs);
    float dcn = dinv[node];
    float2 z = *(const float2*)&h0[(size_t)node * 64 + li * 2];
    float o0 = (1.0f - ALPHA) * (dcn * a0) + ALPHA * z.x;
    float o1 = (1.0f - ALPHA) * (dcn * a1) + ALPHA * z.y;
    if (half == 0) {
        if (last) {
            *(float2*)&hfin[(size_t)node * 64 + li * 2] = make_float2(o0, o1);
        } else {
            unsigned p = (unsigned)f2bf(dcn * o0) | ((unsigned)f2bf(dcn * o1) << 16);
            ((unsigned*)hs_out)[(size_t)node * 32 + li] = p;
        }
    }
}

// ---------------- log_softmax (in-place safe) ----------------
__global__ __launch_bounds__(256) void lsm_kernel(const float* __restrict__ h,
                                                  float* __restrict__ out, int N) {
    int node = blockIdx.x * 4 + (threadIdx.x >> 6);
    if (node >= N) return;
    int lane = threadIdx.x & 63;
    float v = h[(size_t)node * 64 + lane];
    float m = v;
    for (int off = 32; off > 0; off >>= 1) m = fmaxf(m, __shfl_xor(m, off));
    float ex = expf(v - m);
    float s = ex;
    for (int off = 32; off > 0; off >>= 1) s += __shfl_xor(s, off);
    out[(size_t)node * 64 + lane] = (v - m) - logf(s);
}

extern "C" void kernel_launch(void* const* d_in, const int* in_sizes, int n_in,
                              void* d_out, int out_size, void* d_ws, size_t ws_size,
                              hipStream_t stream) {
    const float* x  = (const float*)d_in[0];
    const int*   ei = (const int*)d_in[1];
    const float* W1 = (const float*)d_in[2];
    const float* b1 = (const float*)d_in[3];
    const float* W2 = (const float*)d_in[4];
    const float* b2 = (const float*)d_in[5];
    float* out = (float*)d_out;
    int N = in_sizes[0] / IN_DIM;
    int E = in_sizes[1] / 2;

    char* ws = (char*)d_ws;
    size_t off = 0;
    auto alloc = [&](size_t bytes) -> void* {
        void* p = ws + off;
        off += (bytes + 255) & ~(size_t)255;
        return p;
    };
    float* h0     = (float*)alloc((size_t)N * OUT_DIM * 4);
    float* dinv   = (float*)alloc((size_t)N * 4);
    int*   counts = (int*)alloc((size_t)N * 4);
    int*   fill   = (int*)alloc((size_t)N * 4);
    int*   indptr = (int*)alloc((size_t)(N + 1) * 4);
    int*   bsum   = (int*)alloc(256 * 4);
    int*   boff   = (int*)alloc(256 * 4);
    int*   csr_row= (int*)alloc((size_t)E * 4);
    unsigned short* w1p = (unsigned short*)alloc((size_t)IN_DIM * HID_DIM * 2);
    unsigned short* w2p = (unsigned short*)alloc((size_t)HID_DIM * OUT_DIM * 2);
    unsigned short* hsA = (unsigned short*)alloc((size_t)N * OUT_DIM * 2);
    unsigned short* hsB = (unsigned short*)alloc((size_t)N * OUT_DIM * 2);
    (void)ws_size; (void)n_in; (void)out_size;

    hipMemsetAsync(counts, 0, (size_t)N * 4, stream);
    hipMemsetAsync(fill, 0, (size_t)N * 4, stream);

    prep_w1_kernel<<<(IN_DIM * HID_DIM) / 256, 256, 0, stream>>>(W1, w1p);
    prep_w2_kernel<<<(HID_DIM * OUT_DIM) / 256, 256, 0, stream>>>(W2, w2p);

    hist_kernel<<<(E + 255) / 256, 256, 0, stream>>>(ei, E, counts);
    dinv_kernel<<<(N + 255) / 256, 256, 0, stream>>>(counts, dinv, N);

    int nb = (N + 1023) / 1024;
    scan1_kernel<<<nb, 256, 0, stream>>>(counts, indptr, bsum, N);
    scan2_kernel<<<1, 256, 0, stream>>>(bsum, boff, nb, indptr, N);
    scan3_kernel<<<(N + 255) / 256, 256, 0, stream>>>(indptr, boff, N);
    scatter_kernel<<<(E + 255) / 256, 256, 0, stream>>>(ei, E, indptr, fill, csr_row);

    mlp_mfma_kernel<<<(N + 63) / 64, 256, 0, stream>>>(x, w1p, b1, w2p, b2, h0, N);

    hs_init_kernel<<<(N * 16 + 255) / 256, 256, 0, stream>>>(h0, dinv, hsA, N);

    int pb = (N + 3) / 4;
    for (int it = 0; it < KPROP; ++it) {
        const unsigned short* hin = (it % 2 == 0) ? hsA : hsB;
        unsigned short* hout = (it % 2 == 0) ? hsB : hsA;
        int last = (it == KPROP - 1) ? 1 : 0;
        prop_bf16_kernel<<<pb, 256, 0, stream>>>(hin, h0, dinv, csr_row, indptr,
                                                 hout, out, last, N);
    }
    lsm_kernel<<<pb, 256, 0, stream>>>(out, out, N);
}

// Round 9
// 705.254 us; speedup vs baseline: 1.2924x; 1.1157x over previous
//
#include <hip/hip_runtime.h>

#define IN_DIM  512
#define HID_DIM 256
#define OUT_DIM 64
#define KPROP   5
#define ALPHA   0.1f

#define BKT_SHIFT 9            // 512 dst nodes per bucket
#define PART_EPB  8192         // edges per partition block

typedef short short8v __attribute__((ext_vector_type(8)));
typedef float f32x4   __attribute__((ext_vector_type(4)));

__device__ __forceinline__ unsigned short f2bf(float f) {
    unsigned u = __builtin_bit_cast(unsigned, f);
    unsigned r = (u + 0x7FFFu + ((u >> 16) & 1u)) >> 16;
    return (unsigned short)r;
}
__device__ __forceinline__ float bflo(unsigned v) { return __builtin_bit_cast(float, v << 16); }
__device__ __forceinline__ float bfhi(unsigned v) { return __builtin_bit_cast(float, v & 0xffff0000u); }

// ---------------- degree histogram over dst (col) ----------------
__global__ __launch_bounds__(256) void hist_kernel(const int* __restrict__ ei, int E,
                                                   int* __restrict__ counts) {
    int e = blockIdx.x * 256 + threadIdx.x;
    if (e < E) atomicAdd(&counts[ei[E + e]], 1);
}

__global__ __launch_bounds__(256) void dinv_kernel(const int* __restrict__ counts,
                                                   float* __restrict__ dinv, int N) {
    int i = blockIdx.x * 256 + threadIdx.x;
    if (i < N) dinv[i] = rsqrtf((float)(counts[i] + 1));
}

// ---------------- exclusive scan (3 kernels) ----------------
__global__ __launch_bounds__(256) void scan1_kernel(const int* __restrict__ counts,
                                                    int* __restrict__ indptr,
                                                    int* __restrict__ bsum, int N) {
    __shared__ int sm[256];
    int t = threadIdx.x;
    int base = blockIdx.x * 1024 + t * 4;
    int v0 = 0, v1 = 0, v2 = 0, v3 = 0;
    if (base + 0 < N) v0 = counts[base + 0];
    if (base + 1 < N) v1 = counts[base + 1];
    if (base + 2 < N) v2 = counts[base + 2];
    if (base + 3 < N) v3 = counts[base + 3];
    int s = v0 + v1 + v2 + v3;
    sm[t] = s;
    __syncthreads();
    for (int off = 1; off < 256; off <<= 1) {
        int add = 0;
        if (t >= off) add = sm[t - off];
        __syncthreads();
        if (t >= off) sm[t] += add;
        __syncthreads();
    }
    int run = sm[t] - s;
    if (base + 0 < N) indptr[base + 0] = run; run += v0;
    if (base + 1 < N) indptr[base + 1] = run; run += v1;
    if (base + 2 < N) indptr[base + 2] = run; run += v2;
    if (base + 3 < N) indptr[base + 3] = run;
    if (t == 255) bsum[blockIdx.x] = sm[255];
}

__global__ __launch_bounds__(256) void scan2_kernel(const int* __restrict__ bsum,
                                                    int* __restrict__ boff, int nb,
                                                    int* __restrict__ indptr, int N) {
    __shared__ int sm[256];
    int t = threadIdx.x;
    int v = (t < nb) ? bsum[t] : 0;
    sm[t] = v;
    __syncthreads();
    for (int off = 1; off < 256; off <<= 1) {
        int add = 0;
        if (t >= off) add = sm[t - off];
        __syncthreads();
        if (t >= off) sm[t] += add;
        __syncthreads();
    }
    boff[t] = sm[t] - v;
    if (t == 255) indptr[N] = sm[255];
}

__global__ __launch_bounds__(256) void scan3_kernel(int* __restrict__ indptr,
                                                    const int* __restrict__ boff, int N) {
    int i = blockIdx.x * 256 + threadIdx.x;
    if (i < N) indptr[i] += boff[i >> 10];
}

// ---------------- bucketed CSR build ----------------
// bucketFill[b] starts at the bucket's base offset in the packed array.
__global__ __launch_bounds__(256) void bucket_init_kernel(const int* __restrict__ indptr,
                                                          int* __restrict__ bucketFill,
                                                          int nbkt) {
    int t = blockIdx.x * 256 + threadIdx.x;
    if (t < nbkt) bucketFill[t] = indptr[t << BKT_SHIFT];
}

// per-block counting partition into coarse buckets; packed = (dst&511)<<17 | src
__global__ __launch_bounds__(256) void partition_kernel(const int* __restrict__ ei, int E,
                                                        int* __restrict__ bucketFill,
                                                        int* __restrict__ packed) {
    __shared__ int hist[256];
    __shared__ int base[256];
    int t = threadIdx.x;
    int e0 = blockIdx.x * PART_EPB;
    hist[t] = 0;
    __syncthreads();
#pragma unroll 4
    for (int i = 0; i < PART_EPB / 256; ++i) {
        int e = e0 + i * 256 + t;
        if (e < E) atomicAdd(&hist[ei[E + e] >> BKT_SHIFT], 1);
    }
    __syncthreads();
    int cnt = hist[t];
    if (cnt > 0) base[t] = atomicAdd(&bucketFill[t], cnt);
    __syncthreads();
#pragma unroll 4
    for (int i = 0; i < PART_EPB / 256; ++i) {
        int e = e0 + i * 256 + t;
        if (e < E) {
            int dst = ei[E + e];
            int src = ei[e];
            int b = dst >> BKT_SHIFT;
            int pos = atomicAdd(&base[b], 1);
            packed[pos] = ((dst & 511) << 17) | src;
        }
    }
}

// one block per bucket: exact-dst scatter within an L2-hot csr window,
// fill counters in LDS.
__global__ __launch_bounds__(256) void fine_scatter_kernel(const int* __restrict__ packed,
                                                           const int* __restrict__ indptr,
                                                           int* __restrict__ csr_row, int N) {
    __shared__ int fill[512];
    int b = blockIdx.x;
    int d0 = b << BKT_SHIFT;
    int t = threadIdx.x;
    fill[t] = 0;
    fill[t + 256] = 0;
    __syncthreads();
    int dhi = d0 + 512;
    if (dhi > N) dhi = N;
    int beg = indptr[d0];
    int end = indptr[dhi];
    for (int e = beg + t; e < end; e += 256) {
        unsigned p = (unsigned)packed[e];
        int src = (int)(p & 0x1FFFFu);
        int dl = (int)(p >> 17);
        int pos = indptr[d0 + dl] + atomicAdd(&fill[dl], 1);
        csr_row[pos] = src;
    }
}

// ---------------- weight prep ----------------
__global__ __launch_bounds__(256) void prep_w1_kernel(const float* __restrict__ W1,
                                                      unsigned short* __restrict__ w1p) {
    int idx = blockIdx.x * 256 + threadIdx.x;
    int q = idx >> 14;
    int rem = idx & 16383;
    int c = rem >> 6, j = rem & 63;
    w1p[idx] = f2bf(W1[(size_t)(q * 64 + j) * HID_DIM + c]);
}

__global__ __launch_bounds__(256) void prep_w2_kernel(const float* __restrict__ W2,
                                                      unsigned short* __restrict__ w2p) {
    int idx = blockIdx.x * 256 + threadIdx.x;
    int c = idx >> 8, k = idx & 255;
    w2p[idx] = f2bf(W2[(size_t)k * OUT_DIM + c]);
}

// ---------------- MFMA MLP, T14 async-STAGE, spill-proofed (r8, unchanged) ----------------
struct __align__(16) MlpSmem {
    union {
        struct {
            unsigned short xs[64][72];
            unsigned short ws[256][72];
        };
        unsigned short w2s[64][264];
    };
    unsigned short hid[64][264];
};

__device__ __forceinline__ float4 ldx1(const float* __restrict__ x, int row0, int N,
                                       int t, int i, int q) {
    int e = t * 4 + i * 1024;
    int r = e >> 6, j = e & 63;
    if (row0 + r < N) return *(const float4*)&x[(size_t)(row0 + r) * IN_DIM + q * 64 + j];
    return make_float4(0.f, 0.f, 0.f, 0.f);
}

__global__ __launch_bounds__(256, 2) void mlp_mfma_kernel(const float* __restrict__ x,
                                                          const unsigned short* __restrict__ w1p,
                                                          const float* __restrict__ b1,
                                                          const unsigned short* __restrict__ w2p,
                                                          const float* __restrict__ b2,
                                                          float* __restrict__ h0, int N) {
    __shared__ MlpSmem sm;
    int t = threadIdx.x;
    int w = t >> 6, l = t & 63;
    int l15 = l & 15, l4 = l >> 4;
    int wr0 = w * 16;
    int row0 = blockIdx.x * 64;

    f32x4 acc[16];
#pragma unroll
    for (int i = 0; i < 16; ++i) acc[i] = (f32x4){0.f, 0.f, 0.f, 0.f};

    float4 xr0, xr1, xr2, xr3;
    uint4 wv0, wv1, wv2, wv3, wv4, wv5, wv6, wv7;

#define LOADX(q) do { \
        xr0 = ldx1(x, row0, N, t, 0, (q)); \
        xr1 = ldx1(x, row0, N, t, 1, (q)); \
        xr2 = ldx1(x, row0, N, t, 2, (q)); \
        xr3 = ldx1(x, row0, N, t, 3, (q)); \
    } while (0)
#define LOADW(q) do { \
        const unsigned short* _s = w1p + (q) * 16384; \
        wv0 = *(const uint4*)&_s[t * 8 + 0 * 2048]; \
        wv1 = *(const uint4*)&_s[t * 8 + 1 * 2048]; \
        wv2 = *(const uint4*)&_s[t * 8 + 2 * 2048]; \
        wv3 = *(const uint4*)&_s[t * 8 + 3 * 2048]; \
        wv4 = *(const uint4*)&_s[t * 8 + 4 * 2048]; \
        wv5 = *(const uint4*)&_s[t * 8 + 5 * 2048]; \
        wv6 = *(const uint4*)&_s[t * 8 + 6 * 2048]; \
        wv7 = *(const uint4*)&_s[t * 8 + 7 * 2048]; \
    } while (0)
#define STX(i, v) do { \
        int e = t * 4 + (i) * 1024; \
        int r = e >> 6, j = e & 63; \
        unsigned u0 = (unsigned)f2bf((v).x) | ((unsigned)f2bf((v).y) << 16); \
        unsigned u1 = (unsigned)f2bf((v).z) | ((unsigned)f2bf((v).w) << 16); \
        *(uint2*)&sm.xs[r][j] = make_uint2(u0, u1); \
    } while (0)
#define STW(i, v) do { \
        int e = t * 8 + (i) * 2048; \
        int c = e >> 6, j = e & 63; \
        *(uint4*)&sm.ws[c][j] = (v); \
    } while (0)

    LOADX(0);
    LOADW(0);

    for (int q = 0; q < 8; ++q) {
        __syncthreads();
        STX(0, xr0); STX(1, xr1); STX(2, xr2); STX(3, xr3);
        STW(0, wv0); STW(1, wv1); STW(2, wv2); STW(3, wv3);
        STW(4, wv4); STW(5, wv5); STW(6, wv6); STW(7, wv7);
        __syncthreads();
        if (q < 7) {
            LOADX(q + 1);
            LOADW(q + 1);
        }
#pragma unroll
        for (int s = 0; s < 2; ++s) {
            short8v a = *(const short8v*)&sm.xs[wr0 + l15][s * 32 + l4 * 8];
#pragma unroll
            for (int tc = 0; tc < 16; ++tc) {
                short8v b = *(const short8v*)&sm.ws[tc * 16 + l15][s * 32 + l4 * 8];
                acc[tc] = __builtin_amdgcn_mfma_f32_16x16x32_bf16(a, b, acc[tc], 0, 0, 0);
            }
        }
    }
    __syncthreads();

#pragma unroll
    for (int tc = 0; tc < 16; ++tc) {
        float bv = b1[tc * 16 + l15];
#pragma unroll
        for (int i = 0; i < 4; ++i) {
            float v = fmaxf(acc[tc][i] + bv, 0.f);
            sm.hid[wr0 + l4 * 4 + i][tc * 16 + l15] = f2bf(v);
        }
    }
#pragma unroll
    for (int i = 0; i < 8; ++i) {
        int e = t * 8 + i * 2048;
        int c = e >> 8, k = e & 255;
        *(uint4*)&sm.w2s[c][k] = *(const uint4*)&w2p[e];
    }
    __syncthreads();

    f32x4 acc2[4];
#pragma unroll
    for (int i = 0; i < 4; ++i) acc2[i] = (f32x4){0.f, 0.f, 0.f, 0.f};
#pragma unroll
    for (int s = 0; s < 8; ++s) {
        short8v a = *(const short8v*)&sm.hid[wr0 + l15][s * 32 + l4 * 8];
#pragma unroll
        for (int tc = 0; tc < 4; ++tc) {
            short8v b = *(const short8v*)&sm.w2s[tc * 16 + l15][s * 32 + l4 * 8];
            acc2[tc] = __builtin_amdgcn_mfma_f32_16x16x32_bf16(a, b, acc2[tc], 0, 0, 0);
        }
    }
#pragma unroll
    for (int tc = 0; tc < 4; ++tc) {
        float bv = b2[tc * 16 + l15];
#pragma unroll
        for (int i = 0; i < 4; ++i) {
            int row = row0 + wr0 + l4 * 4 + i;
            if (row < N) h0[(size_t)row * OUT_DIM + tc * 16 + l15] = acc2[tc][i] + bv;
        }
    }
#undef LOADX
#undef LOADW
#undef STX
#undef STW
}

// ---------------- hs init: hs[i] = bf16(dinv[i] * h0[i]) ----------------
__global__ __launch_bounds__(256) void hs_init_kernel(const float* __restrict__ h0,
                                                      const float* __restrict__ dinv,
                                                      unsigned short* __restrict__ hs, int N) {
    int idx = blockIdx.x * 256 + threadIdx.x;
    if (idx >= N * 16) return;
    int node = idx >> 4;
    int j = (idx & 15) * 4;
    float d = dinv[node];
    float4 v = *(const float4*)&h0[(size_t)node * 64 + j];
    ushort4 o;
    o.x = f2bf(d * v.x);
    o.y = f2bf(d * v.y);
    o.z = f2bf(d * v.z);
    o.w = f2bf(d * v.w);
    *(ushort4*)&hs[(size_t)node * 64 + j] = o;
}

// ---------------- propagation, bf16 prescaled + idx software pipeline ----------------
__global__ __launch_bounds__(256) void prop_bf16_kernel(const unsigned short* __restrict__ hs,
                                                        const float* __restrict__ h0,
                                                        const float* __restrict__ dinv,
                                                        const int* __restrict__ csr_row,
                                                        const int* __restrict__ indptr,
                                                        unsigned short* __restrict__ hs_out,
                                                        float* __restrict__ hfin,
                                                        int last, int N) {
    int node = blockIdx.x * 4 + (threadIdx.x >> 6);
    if (node >= N) return;
    int l = threadIdx.x & 63;
    int half = l >> 5, li = l & 31;
    const unsigned* hs32 = (const unsigned*)hs;
    int beg = indptr[node], end = indptr[node + 1];
    float a0 = 0.f, a1 = 0.f;
    int e = beg;
    if (e + 8 <= end) {
        int r0 = csr_row[e + 0 + half];
        int r1 = csr_row[e + 2 + half];
        int r2 = csr_row[e + 4 + half];
        int r3 = csr_row[e + 6 + half];
        while (true) {
            int eb = (e + 16 <= end) ? (e + 8) : beg;
            int n0 = csr_row[eb + 0 + half];
            int n1 = csr_row[eb + 2 + half];
            int n2 = csr_row[eb + 4 + half];
            int n3 = csr_row[eb + 6 + half];
            unsigned v0 = hs32[(size_t)r0 * 32 + li];
            unsigned v1 = hs32[(size_t)r1 * 32 + li];
            unsigned v2 = hs32[(size_t)r2 * 32 + li];
            unsigned v3 = hs32[(size_t)r3 * 32 + li];
            a0 += bflo(v0); a1 += bfhi(v0);
            a0 += bflo(v1); a1 += bfhi(v1);
            a0 += bflo(v2); a1 += bfhi(v2);
            a0 += bflo(v3); a1 += bfhi(v3);
            e += 8;
            if (e + 8 > end) break;
            r0 = n0; r1 = n1; r2 = n2; r3 = n3;
        }
    }
    for (; e + 2 <= end; e += 2) {
        int r = csr_row[e + half];
        unsigned v = hs32[(size_t)r * 32 + li];
        a0 += bflo(v); a1 += bfhi(v);
    }
    if (e < end && half == 0) {
        int r = csr_row[e];
        unsigned v = hs32[(size_t)r * 32 + li];
        a0 += bflo(v); a1 += bfhi(v);
    }
    a0 += __shfl_xor(a0, 32);
    a1 += __shfl_xor(a1, 32);
    unsigned vs = hs32[(size_t)node * 32 + li];  // self loop
    a0 += bflo(vs);
    a1 += bfhi(vs);
    float dcn = dinv[node];
    float2 z = *(const float2*)&h0[(size_t)node * 64 + li * 2];
    float o0 = (1.0f - ALPHA) * (dcn * a0) + ALPHA * z.x;
    float o1 = (1.0f - ALPHA) * (dcn * a1) + ALPHA * z.y;
    if (half == 0) {
        if (last) {
            *(float2*)&hfin[(size_t)node * 64 + li * 2] = make_float2(o0, o1);
        } else {
            unsigned p = (unsigned)f2bf(dcn * o0) | ((unsigned)f2bf(dcn * o1) << 16);
            ((unsigned*)hs_out)[(size_t)node * 32 + li] = p;
        }
    }
}

// ---------------- log_softmax (in-place safe) ----------------
__global__ __launch_bounds__(256) void lsm_kernel(const float* __restrict__ h,
                                                  float* __restrict__ out, int N) {
    int node = blockIdx.x * 4 + (threadIdx.x >> 6);
    if (node >= N) return;
    int lane = threadIdx.x & 63;
    float v = h[(size_t)node * 64 + lane];
    float m = v;
    for (int off = 32; off > 0; off >>= 1) m = fmaxf(m, __shfl_xor(m, off));
    float ex = expf(v - m);
    float s = ex;
    for (int off = 32; off > 0; off >>= 1) s += __shfl_xor(s, off);
    out[(size_t)node * 64 + lane] = (v - m) - logf(s);
}

extern "C" void kernel_launch(void* const* d_in, const int* in_sizes, int n_in,
                              void* d_out, int out_size, void* d_ws, size_t ws_size,
                              hipStream_t stream) {
    const float* x  = (const float*)d_in[0];
    const int*   ei = (const int*)d_in[1];
    const float* W1 = (const float*)d_in[2];
    const float* b1 = (const float*)d_in[3];
    const float* W2 = (const float*)d_in[4];
    const float* b2 = (const float*)d_in[5];
    float* out = (float*)d_out;
    int N = in_sizes[0] / IN_DIM;
    int E = in_sizes[1] / 2;
    int nbkt = (N + 511) >> BKT_SHIFT;   // 196 for N=100000 (<=256 assumed)

    char* ws = (char*)d_ws;
    size_t off = 0;
    auto alloc = [&](size_t bytes) -> void* {
        void* p = ws + off;
        off += (bytes + 255) & ~(size_t)255;
        return p;
    };
    float* h0     = (float*)alloc((size_t)N * OUT_DIM * 4);
    float* dinv   = (float*)alloc((size_t)N * 4);
    int*   counts = (int*)alloc((size_t)N * 4);
    int*   indptr = (int*)alloc((size_t)(N + 1) * 4);
    int*   bsum   = (int*)alloc(256 * 4);
    int*   boff   = (int*)alloc(256 * 4);
    int*   bfill  = (int*)alloc(256 * 4);
    int*   packed = (int*)alloc((size_t)E * 4);
    int*   csr_row= (int*)alloc((size_t)E * 4);
    unsigned short* w1p = (unsigned short*)alloc((size_t)IN_DIM * HID_DIM * 2);
    unsigned short* w2p = (unsigned short*)alloc((size_t)HID_DIM * OUT_DIM * 2);
    unsigned short* hsA = (unsigned short*)alloc((size_t)N * OUT_DIM * 2);
    unsigned short* hsB = (unsigned short*)alloc((size_t)N * OUT_DIM * 2);
    (void)ws_size; (void)n_in; (void)out_size;

    hipMemsetAsync(counts, 0, (size_t)N * 4, stream);

    prep_w1_kernel<<<(IN_DIM * HID_DIM) / 256, 256, 0, stream>>>(W1, w1p);
    prep_w2_kernel<<<(HID_DIM * OUT_DIM) / 256, 256, 0, stream>>>(W2, w2p);

    hist_kernel<<<(E + 255) / 256, 256, 0, stream>>>(ei, E, counts);
    dinv_kernel<<<(N + 255) / 256, 256, 0, stream>>>(counts, dinv, N);

    int nb = (N + 1023) / 1024;
    scan1_kernel<<<nb, 256, 0, stream>>>(counts, indptr, bsum, N);
    scan2_kernel<<<1, 256, 0, stream>>>(bsum, boff, nb, indptr, N);
    scan3_kernel<<<(N + 255) / 256, 256, 0, stream>>>(indptr, boff, N);

    bucket_init_kernel<<<1, 256, 0, stream>>>(indptr, bfill, nbkt);
    partition_kernel<<<(E + PART_EPB - 1) / PART_EPB, 256, 0, stream>>>(ei, E, bfill, packed);
    fine_scatter_kernel<<<nbkt, 256, 0, stream>>>(packed, indptr, csr_row, N);

    mlp_mfma_kernel<<<(N + 63) / 64, 256, 0, stream>>>(x, w1p, b1, w2p, b2, h0, N);

    hs_init_kernel<<<(N * 16 + 255) / 256, 256, 0, stream>>>(h0, dinv, hsA, N);

    int pb = (N + 3) / 4;
    for (int it = 0; it < KPROP; ++it) {
        const unsigned short* hin = (it % 2 == 0) ? hsA : hsB;
        unsigned short* hout = (it % 2 == 0) ? hsB : hsA;
        int last = (it == KPROP - 1) ? 1 : 0;
        prop_bf16_kernel<<<pb, 256, 0, stream>>>(hin, h0, dinv, csr_row, indptr,
                                                 hout, out, last, N);
    }
    lsm_kernel<<<pb, 256, 0, stream>>>(out, out, N);
}

// Round 10
// 594.088 us; speedup vs baseline: 1.5343x; 1.1871x over previous
//
#include <hip/hip_runtime.h>

#define IN_DIM  512
#define HID_DIM 256
#define OUT_DIM 64
#define KPROP   5
#define ALPHA   0.1f

#define BKT_SHIFT 9            // 512 dst nodes per bucket
#define PART_EPB  8192         // edges per partition block

typedef short short8v __attribute__((ext_vector_type(8)));
typedef float f32x4   __attribute__((ext_vector_type(4)));

__device__ __forceinline__ unsigned short f2bf(float f) {
    unsigned u = __builtin_bit_cast(unsigned, f);
    unsigned r = (u + 0x7FFFu + ((u >> 16) & 1u)) >> 16;
    return (unsigned short)r;
}
__device__ __forceinline__ float bflo(unsigned v) { return __builtin_bit_cast(float, v << 16); }
__device__ __forceinline__ float bfhi(unsigned v) { return __builtin_bit_cast(float, v & 0xffff0000u); }

// ---------------- bucket-level edge count (few global atomics) ----------------
__global__ __launch_bounds__(256) void bucket_count_kernel(const int* __restrict__ ei, int E,
                                                           int* __restrict__ bucketCnt) {
    __shared__ int hist[256];
    int t = threadIdx.x;
    hist[t] = 0;
    __syncthreads();
    int e0 = blockIdx.x * PART_EPB;
#pragma unroll 4
    for (int i = 0; i < PART_EPB / 256; ++i) {
        int e = e0 + i * 256 + t;
        if (e < E) atomicAdd(&hist[ei[E + e] >> BKT_SHIFT], 1);
    }
    __syncthreads();
    if (hist[t] > 0) atomicAdd(&bucketCnt[t], hist[t]);
}

// ---------------- bucket scan: bases + fill init (1 block) ----------------
__global__ __launch_bounds__(256) void bucket_scan_kernel(const int* __restrict__ bucketCnt,
                                                          int* __restrict__ bucketBase,
                                                          int* __restrict__ bucketFill,
                                                          int* __restrict__ indptr,
                                                          int E, int N) {
    __shared__ int sm[256];
    int t = threadIdx.x;
    int v = bucketCnt[t];   // entries >= nbkt stay 0
    sm[t] = v;
    __syncthreads();
    for (int off = 1; off < 256; off <<= 1) {
        int add = 0;
        if (t >= off) add = sm[t - off];
        __syncthreads();
        if (t >= off) sm[t] += add;
        __syncthreads();
    }
    int base = sm[t] - v;
    bucketBase[t] = base;
    bucketFill[t] = base;
    if (t == 0) indptr[N] = E;
}

// ---------------- partition into coarse buckets; packed = (dst&511)<<17 | src ----------------
__global__ __launch_bounds__(256) void partition_kernel(const int* __restrict__ ei, int E,
                                                        int* __restrict__ bucketFill,
                                                        int* __restrict__ packed) {
    __shared__ int hist[256];
    __shared__ int base[256];
    int t = threadIdx.x;
    int e0 = blockIdx.x * PART_EPB;
    hist[t] = 0;
    __syncthreads();
#pragma unroll 4
    for (int i = 0; i < PART_EPB / 256; ++i) {
        int e = e0 + i * 256 + t;
        if (e < E) atomicAdd(&hist[ei[E + e] >> BKT_SHIFT], 1);
    }
    __syncthreads();
    int cnt = hist[t];
    if (cnt > 0) base[t] = atomicAdd(&bucketFill[t], cnt);
    __syncthreads();
#pragma unroll 4
    for (int i = 0; i < PART_EPB / 256; ++i) {
        int e = e0 + i * 256 + t;
        if (e < E) {
            int dst = ei[E + e];
            int src = ei[e];
            int b = dst >> BKT_SHIFT;
            int pos = atomicAdd(&base[b], 1);
            packed[pos] = ((dst & 511) << 17) | src;
        }
    }
}

// ---------------- fused per-bucket: node hist + indptr + dinv + scatter ----------------
// One block per bucket. All node-level counting in LDS; writes land in an
// L2-hot 64KB window. Replaces hist/dinv/scan1-3/fine_scatter.
__global__ __launch_bounds__(256) void fine_kernel(const int* __restrict__ packed,
                                                   const int* __restrict__ bucketBase,
                                                   const int* __restrict__ bucketCnt,
                                                   int* __restrict__ csr_row,
                                                   int* __restrict__ indptr,
                                                   float* __restrict__ dinv, int N) {
    __shared__ int cnt[512];
    __shared__ int pre[512];
    __shared__ int fill[512];
    __shared__ int sm[256];
    int b = blockIdx.x;
    int t = threadIdx.x;
    int d0 = b << BKT_SHIFT;
    int nd = N - d0;
    if (nd > 512) nd = 512;
    cnt[t] = 0; cnt[t + 256] = 0;
    fill[t] = 0; fill[t + 256] = 0;
    __syncthreads();
    int beg = bucketBase[b];
    int end = beg + bucketCnt[b];
    for (int e = beg + t; e < end; e += 256)
        atomicAdd(&cnt[((unsigned)packed[e]) >> 17], 1);
    __syncthreads();
    // 512-wide exclusive scan (thread t covers 2t, 2t+1)
    int c0 = cnt[2 * t], c1 = cnt[2 * t + 1];
    int s = c0 + c1;
    sm[t] = s;
    __syncthreads();
    for (int off = 1; off < 256; off <<= 1) {
        int add = 0;
        if (t >= off) add = sm[t - off];
        __syncthreads();
        if (t >= off) sm[t] += add;
        __syncthreads();
    }
    int ex = sm[t] - s;
    pre[2 * t] = ex;
    pre[2 * t + 1] = ex + c0;
    __syncthreads();
    for (int dl = t; dl < nd; dl += 256) {
        indptr[d0 + dl] = beg + pre[dl];
        dinv[d0 + dl] = rsqrtf((float)(cnt[dl] + 1));
    }
    for (int e = beg + t; e < end; e += 256) {
        unsigned p = (unsigned)packed[e];
        int dl = (int)(p >> 17);
        int src = (int)(p & 0x1FFFFu);
        int pos = beg + pre[dl] + atomicAdd(&fill[dl], 1);
        csr_row[pos] = src;
    }
}

// ---------------- weight prep ----------------
__global__ __launch_bounds__(256) void prep_w1_kernel(const float* __restrict__ W1,
                                                      unsigned short* __restrict__ w1p) {
    int idx = blockIdx.x * 256 + threadIdx.x;
    int q = idx >> 14;
    int rem = idx & 16383;
    int c = rem >> 6, j = rem & 63;
    w1p[idx] = f2bf(W1[(size_t)(q * 64 + j) * HID_DIM + c]);
}

__global__ __launch_bounds__(256) void prep_w2_kernel(const float* __restrict__ W2,
                                                      unsigned short* __restrict__ w2p) {
    int idx = blockIdx.x * 256 + threadIdx.x;
    int c = idx >> 8, k = idx & 255;
    w2p[idx] = f2bf(W2[(size_t)k * OUT_DIM + c]);
}

// ---------------- MFMA MLP, T14 async-STAGE, spill-proofed (r8, unchanged) ----------------
struct __align__(16) MlpSmem {
    union {
        struct {
            unsigned short xs[64][72];
            unsigned short ws[256][72];
        };
        unsigned short w2s[64][264];
    };
    unsigned short hid[64][264];
};

__device__ __forceinline__ float4 ldx1(const float* __restrict__ x, int row0, int N,
                                       int t, int i, int q) {
    int e = t * 4 + i * 1024;
    int r = e >> 6, j = e & 63;
    if (row0 + r < N) return *(const float4*)&x[(size_t)(row0 + r) * IN_DIM + q * 64 + j];
    return make_float4(0.f, 0.f, 0.f, 0.f);
}

__global__ __launch_bounds__(256, 2) void mlp_mfma_kernel(const float* __restrict__ x,
                                                          const unsigned short* __restrict__ w1p,
                                                          const float* __restrict__ b1,
                                                          const unsigned short* __restrict__ w2p,
                                                          const float* __restrict__ b2,
                                                          float* __restrict__ h0, int N) {
    __shared__ MlpSmem sm;
    int t = threadIdx.x;
    int w = t >> 6, l = t & 63;
    int l15 = l & 15, l4 = l >> 4;
    int wr0 = w * 16;
    int row0 = blockIdx.x * 64;

    f32x4 acc[16];
#pragma unroll
    for (int i = 0; i < 16; ++i) acc[i] = (f32x4){0.f, 0.f, 0.f, 0.f};

    float4 xr0, xr1, xr2, xr3;
    uint4 wv0, wv1, wv2, wv3, wv4, wv5, wv6, wv7;

#define LOADX(q) do { \
        xr0 = ldx1(x, row0, N, t, 0, (q)); \
        xr1 = ldx1(x, row0, N, t, 1, (q)); \
        xr2 = ldx1(x, row0, N, t, 2, (q)); \
        xr3 = ldx1(x, row0, N, t, 3, (q)); \
    } while (0)
#define LOADW(q) do { \
        const unsigned short* _s = w1p + (q) * 16384; \
        wv0 = *(const uint4*)&_s[t * 8 + 0 * 2048]; \
        wv1 = *(const uint4*)&_s[t * 8 + 1 * 2048]; \
        wv2 = *(const uint4*)&_s[t * 8 + 2 * 2048]; \
        wv3 = *(const uint4*)&_s[t * 8 + 3 * 2048]; \
        wv4 = *(const uint4*)&_s[t * 8 + 4 * 2048]; \
        wv5 = *(const uint4*)&_s[t * 8 + 5 * 2048]; \
        wv6 = *(const uint4*)&_s[t * 8 + 6 * 2048]; \
        wv7 = *(const uint4*)&_s[t * 8 + 7 * 2048]; \
    } while (0)
#define STX(i, v) do { \
        int e = t * 4 + (i) * 1024; \
        int r = e >> 6, j = e & 63; \
        unsigned u0 = (unsigned)f2bf((v).x) | ((unsigned)f2bf((v).y) << 16); \
        unsigned u1 = (unsigned)f2bf((v).z) | ((unsigned)f2bf((v).w) << 16); \
        *(uint2*)&sm.xs[r][j] = make_uint2(u0, u1); \
    } while (0)
#define STW(i, v) do { \
        int e = t * 8 + (i) * 2048; \
        int c = e >> 6, j = e & 63; \
        *(uint4*)&sm.ws[c][j] = (v); \
    } while (0)

    LOADX(0);
    LOADW(0);

    for (int q = 0; q < 8; ++q) {
        __syncthreads();
        STX(0, xr0); STX(1, xr1); STX(2, xr2); STX(3, xr3);
        STW(0, wv0); STW(1, wv1); STW(2, wv2); STW(3, wv3);
        STW(4, wv4); STW(5, wv5); STW(6, wv6); STW(7, wv7);
        __syncthreads();
        if (q < 7) {
            LOADX(q + 1);
            LOADW(q + 1);
        }
#pragma unroll
        for (int s = 0; s < 2; ++s) {
            short8v a = *(const short8v*)&sm.xs[wr0 + l15][s * 32 + l4 * 8];
#pragma unroll
            for (int tc = 0; tc < 16; ++tc) {
                short8v b = *(const short8v*)&sm.ws[tc * 16 + l15][s * 32 + l4 * 8];
                acc[tc] = __builtin_amdgcn_mfma_f32_16x16x32_bf16(a, b, acc[tc], 0, 0, 0);
            }
        }
    }
    __syncthreads();

#pragma unroll
    for (int tc = 0; tc < 16; ++tc) {
        float bv = b1[tc * 16 + l15];
#pragma unroll
        for (int i = 0; i < 4; ++i) {
            float v = fmaxf(acc[tc][i] + bv, 0.f);
            sm.hid[wr0 + l4 * 4 + i][tc * 16 + l15] = f2bf(v);
        }
    }
#pragma unroll
    for (int i = 0; i < 8; ++i) {
        int e = t * 8 + i * 2048;
        int c = e >> 8, k = e & 255;
        *(uint4*)&sm.w2s[c][k] = *(const uint4*)&w2p[e];
    }
    __syncthreads();

    f32x4 acc2[4];
#pragma unroll
    for (int i = 0; i < 4; ++i) acc2[i] = (f32x4){0.f, 0.f, 0.f, 0.f};
#pragma unroll
    for (int s = 0; s < 8; ++s) {
        short8v a = *(const short8v*)&sm.hid[wr0 + l15][s * 32 + l4 * 8];
#pragma unroll
        for (int tc = 0; tc < 4; ++tc) {
            short8v b = *(const short8v*)&sm.w2s[tc * 16 + l15][s * 32 + l4 * 8];
            acc2[tc] = __builtin_amdgcn_mfma_f32_16x16x32_bf16(a, b, acc2[tc], 0, 0, 0);
        }
    }
#pragma unroll
    for (int tc = 0; tc < 4; ++tc) {
        float bv = b2[tc * 16 + l15];
#pragma unroll
        for (int i = 0; i < 4; ++i) {
            int row = row0 + wr0 + l4 * 4 + i;
            if (row < N) h0[(size_t)row * OUT_DIM + tc * 16 + l15] = acc2[tc][i] + bv;
        }
    }
#undef LOADX
#undef LOADW
#undef STX
#undef STW
}

// ---------------- hs init: hs[i] = bf16(dinv[i] * h0[i]) ----------------
__global__ __launch_bounds__(256) void hs_init_kernel(const float* __restrict__ h0,
                                                      const float* __restrict__ dinv,
                                                      unsigned short* __restrict__ hs, int N) {
    int idx = blockIdx.x * 256 + threadIdx.x;
    if (idx >= N * 16) return;
    int node = idx >> 4;
    int j = (idx & 15) * 4;
    float d = dinv[node];
    float4 v = *(const float4*)&h0[(size_t)node * 64 + j];
    ushort4 o;
    o.x = f2bf(d * v.x);
    o.y = f2bf(d * v.y);
    o.z = f2bf(d * v.z);
    o.w = f2bf(d * v.w);
    *(ushort4*)&hs[(size_t)node * 64 + j] = o;
}

// ---------------- propagation, bf16 prescaled + idx software pipeline ----------------
__global__ __launch_bounds__(256) void prop_bf16_kernel(const unsigned short* __restrict__ hs,
                                                        const float* __restrict__ h0,
                                                        const float* __restrict__ dinv,
                                                        const int* __restrict__ csr_row,
                                                        const int* __restrict__ indptr,
                                                        unsigned short* __restrict__ hs_out,
                                                        float* __restrict__ hfin,
                                                        int last, int N) {
    int node = blockIdx.x * 4 + (threadIdx.x >> 6);
    if (node >= N) return;
    int l = threadIdx.x & 63;
    int half = l >> 5, li = l & 31;
    const unsigned* hs32 = (const unsigned*)hs;
    int beg = indptr[node], end = indptr[node + 1];
    float a0 = 0.f, a1 = 0.f;
    int e = beg;
    if (e + 8 <= end) {
        int r0 = csr_row[e + 0 + half];
        int r1 = csr_row[e + 2 + half];
        int r2 = csr_row[e + 4 + half];
        int r3 = csr_row[e + 6 + half];
        while (true) {
            int eb = (e + 16 <= end) ? (e + 8) : beg;
            int n0 = csr_row[eb + 0 + half];
            int n1 = csr_row[eb + 2 + half];
            int n2 = csr_row[eb + 4 + half];
            int n3 = csr_row[eb + 6 + half];
            unsigned v0 = hs32[(size_t)r0 * 32 + li];
            unsigned v1 = hs32[(size_t)r1 * 32 + li];
            unsigned v2 = hs32[(size_t)r2 * 32 + li];
            unsigned v3 = hs32[(size_t)r3 * 32 + li];
            a0 += bflo(v0); a1 += bfhi(v0);
            a0 += bflo(v1); a1 += bfhi(v1);
            a0 += bflo(v2); a1 += bfhi(v2);
            a0 += bflo(v3); a1 += bfhi(v3);
            e += 8;
            if (e + 8 > end) break;
            r0 = n0; r1 = n1; r2 = n2; r3 = n3;
        }
    }
    for (; e + 2 <= end; e += 2) {
        int r = csr_row[e + half];
        unsigned v = hs32[(size_t)r * 32 + li];
        a0 += bflo(v); a1 += bfhi(v);
    }
    if (e < end && half == 0) {
        int r = csr_row[e];
        unsigned v = hs32[(size_t)r * 32 + li];
        a0 += bflo(v); a1 += bfhi(v);
    }
    a0 += __shfl_xor(a0, 32);
    a1 += __shfl_xor(a1, 32);
    unsigned vs = hs32[(size_t)node * 32 + li];  // self loop
    a0 += bflo(vs);
    a1 += bfhi(vs);
    float dcn = dinv[node];
    float2 z = *(const float2*)&h0[(size_t)node * 64 + li * 2];
    float o0 = (1.0f - ALPHA) * (dcn * a0) + ALPHA * z.x;
    float o1 = (1.0f - ALPHA) * (dcn * a1) + ALPHA * z.y;
    if (half == 0) {
        if (last) {
            *(float2*)&hfin[(size_t)node * 64 + li * 2] = make_float2(o0, o1);
        } else {
            unsigned p = (unsigned)f2bf(dcn * o0) | ((unsigned)f2bf(dcn * o1) << 16);
            ((unsigned*)hs_out)[(size_t)node * 32 + li] = p;
        }
    }
}

// ---------------- log_softmax (in-place safe) ----------------
__global__ __launch_bounds__(256) void lsm_kernel(const float* __restrict__ h,
                                                  float* __restrict__ out, int N) {
    int node = blockIdx.x * 4 + (threadIdx.x >> 6);
    if (node >= N) return;
    int lane = threadIdx.x & 63;
    float v = h[(size_t)node * 64 + lane];
    float m = v;
    for (int off = 32; off > 0; off >>= 1) m = fmaxf(m, __shfl_xor(m, off));
    float ex = expf(v - m);
    float s = ex;
    for (int off = 32; off > 0; off >>= 1) s += __shfl_xor(s, off);
    out[(size_t)node * 64 + lane] = (v - m) - logf(s);
}

extern "C" void kernel_launch(void* const* d_in, const int* in_sizes, int n_in,
                              void* d_out, int out_size, void* d_ws, size_t ws_size,
                              hipStream_t stream) {
    const float* x  = (const float*)d_in[0];
    const int*   ei = (const int*)d_in[1];
    const float* W1 = (const float*)d_in[2];
    const float* b1 = (const float*)d_in[3];
    const float* W2 = (const float*)d_in[4];
    const float* b2 = (const float*)d_in[5];
    float* out = (float*)d_out;
    int N = in_sizes[0] / IN_DIM;
    int E = in_sizes[1] / 2;
    int nbkt = (N + 511) >> BKT_SHIFT;   // 196 for N=100000 (<=256 assumed)

    char* ws = (char*)d_ws;
    size_t off = 0;
    auto alloc = [&](size_t bytes) -> void* {
        void* p = ws + off;
        off += (bytes + 255) & ~(size_t)255;
        return p;
    };
    float* h0     = (float*)alloc((size_t)N * OUT_DIM * 4);
    float* dinv   = (float*)alloc((size_t)N * 4);
    int*   indptr = (int*)alloc((size_t)(N + 1) * 4);
    int*   bcnt   = (int*)alloc(256 * 4);
    int*   bbase  = (int*)alloc(256 * 4);
    int*   bfill  = (int*)alloc(256 * 4);
    int*   packed = (int*)alloc((size_t)E * 4);
    int*   csr_row= (int*)alloc((size_t)E * 4);
    unsigned short* w1p = (unsigned short*)alloc((size_t)IN_DIM * HID_DIM * 2);
    unsigned short* w2p = (unsigned short*)alloc((size_t)HID_DIM * OUT_DIM * 2);
    unsigned short* hsA = (unsigned short*)alloc((size_t)N * OUT_DIM * 2);
    unsigned short* hsB = (unsigned short*)alloc((size_t)N * OUT_DIM * 2);
    (void)ws_size; (void)n_in; (void)out_size;

    hipMemsetAsync(bcnt, 0, 256 * 4, stream);

    prep_w1_kernel<<<(IN_DIM * HID_DIM) / 256, 256, 0, stream>>>(W1, w1p);
    prep_w2_kernel<<<(HID_DIM * OUT_DIM) / 256, 256, 0, stream>>>(W2, w2p);

    int pgrid = (E + PART_EPB - 1) / PART_EPB;
    bucket_count_kernel<<<pgrid, 256, 0, stream>>>(ei, E, bcnt);
    bucket_scan_kernel<<<1, 256, 0, stream>>>(bcnt, bbase, bfill, indptr, E, N);
    partition_kernel<<<pgrid, 256, 0, stream>>>(ei, E, bfill, packed);
    fine_kernel<<<nbkt, 256, 0, stream>>>(packed, bbase, bcnt, csr_row, indptr, dinv, N);

    mlp_mfma_kernel<<<(N + 63) / 64, 256, 0, stream>>>(x, w1p, b1, w2p, b2, h0, N);

    hs_init_kernel<<<(N * 16 + 255) / 256, 256, 0, stream>>>(h0, dinv, hsA, N);

    int pb = (N + 3) / 4;
    for (int it = 0; it < KPROP; ++it) {
        const unsigned short* hin = (it % 2 == 0) ? hsA : hsB;
        unsigned short* hout = (it % 2 == 0) ? hsB : hsA;
        int last = (it == KPROP - 1) ? 1 : 0;
        prop_bf16_kernel<<<pb, 256, 0, stream>>>(hin, h0, dinv, csr_row, indptr,
                                                 hout, out, last, N);
    }
    lsm_kernel<<<pb, 256, 0, stream>>>(out, out, N);
}